// Round 1
// baseline (164.417 us; speedup 1.0000x reference)
//
#include <hip/hip_runtime.h>
#include <math.h>

// Problem constants
#define D      50
#define MM     128      // M
#define LL     512      // L
#define BB     64       // B
#define KS     136      // LDS V-row stride in shorts (272 B = 16*17, 16B-aligned rows)
#define KSU    68       // uints per V row
#define LT     64       // tokens per block
#define NCH    8        // L / LT
#define NTHREADS 256

typedef __attribute__((ext_vector_type(8))) short  short8;   // 8 bf16 = 4 VGPR
typedef __attribute__((ext_vector_type(4))) float  float4v;  // MFMA C/D

// round-to-nearest bf16 split: x ~= hi + lo, |x - hi - lo| <= ~2^-18 |x|
__device__ __forceinline__ void bsplit(float x, short& hi, short& lo) {
    unsigned u = __float_as_uint(x);
    unsigned r = u + 0x7FFFu + ((u >> 16) & 1u);
    hi = (short)(r >> 16);
    float res = x - __uint_as_float(r & 0xFFFF0000u);
    unsigned u2 = __float_as_uint(res);
    unsigned r2 = u2 + 0x7FFFu + ((u2 >> 16) & 1u);
    lo = (short)(r2 >> 16);
}

// split a pair, pack hi halves and lo halves into uints (little-endian: elem d in low16)
__device__ __forceinline__ void bsplit2(float x0, float x1, unsigned& hiU, unsigned& loU) {
    short h0, l0, h1, l1;
    bsplit(x0, h0, l0);
    bsplit(x1, h1, l1);
    hiU = (unsigned)(unsigned short)h0 | ((unsigned)(unsigned short)h1 << 16);
    loU = (unsigned)(unsigned short)l0 | ((unsigned)(unsigned short)l1 << 16);
}

// Prep, 73 blocks:
//  blocks 0..7 : per-lane MFMA B-fragments (bf16 hi/lo, real/imag) + 1/||row||^2
//  block  8    : zero-init out (harness poisons 0xAA)
//  blocks 9..72: per-b softmax over mix logits -> ws_w[b][l]  (dedup: was 8x per chunk)
__global__ void __launch_bounds__(NTHREADS)
qdnn_prep(const int*   __restrict__ x,
          const float* __restrict__ mix_table,
          const float* __restrict__ kernel_real,
          const float* __restrict__ kernel_imag,
          float* __restrict__ out,
          short* __restrict__ ws_frag,    // [32 (ntile,ks)][4 kinds][64 lanes][8 shorts]
          float* __restrict__ ws_inorm,   // [128] 1/||row||^2
          float* __restrict__ ws_w)       // [64][512]
{
    __shared__ float s_nr[NTHREADS];
    __shared__ float s_red[8];
    const int tid = threadIdx.x;
    const int blk = blockIdx.x;

    if (blk < 8) {
        // ---- B-fragment build. B'[m][k]: Br = [kr|ki|0], Bi = [-ki|kr|0] along k.
        // lane frag: B'[m = ntile*16 + (lane&15)][k = kstep*32 + (lane>>4)*8 + j]
        const int ntile = blk;
        const int lane  = tid & 63;
        const int kstep = tid >> 6;
        const int col   = lane & 15;
        const int g     = lane >> 4;
        const int m     = ntile * 16 + col;
        const float* krow = kernel_real + m * D;
        const float* irow = kernel_imag + m * D;

        short8 fr_hi, fr_lo, fi_hi, fi_lo;
        float np = 0.0f;
        #pragma unroll
        for (int j = 0; j < 8; ++j) {
            const int k = kstep * 32 + g * 8 + j;
            float br = 0.0f, bi = 0.0f;
            if (k < D) {
                const float a = krow[k], c = irow[k];
                br = a; bi = -c;
                np = fmaf(a, a, fmaf(c, c, np));   // counted once (k<50 only)
            } else if (k < 2 * D) {
                const float a = krow[k - D], c = irow[k - D];
                br = c; bi = a;
            }
            short h, l;
            bsplit(br, h, l); fr_hi[j] = h; fr_lo[j] = l;
            bsplit(bi, h, l); fi_hi[j] = h; fi_lo[j] = l;
        }
        const size_t fb = (size_t)((ntile * 4 + kstep) * 4) * 64 * 8;
        *(short8*)(ws_frag + fb + (size_t)(0 * 64 + lane) * 8) = fr_hi;
        *(short8*)(ws_frag + fb + (size_t)(1 * 64 + lane) * 8) = fr_lo;
        *(short8*)(ws_frag + fb + (size_t)(2 * 64 + lane) * 8) = fi_hi;
        *(short8*)(ws_frag + fb + (size_t)(3 * 64 + lane) * 8) = fi_lo;

        s_nr[tid] = np;
        __syncthreads();
        if (tid < 16) {                  // threads with lane&15==tid cover all k once
            float s = 0.0f;
            #pragma unroll
            for (int u = 0; u < 16; ++u) s += s_nr[tid + 16 * u];
            ws_inorm[ntile * 16 + tid] = 1.0f / s;
        }
    } else if (blk == 8) {
        // ---- zero-init output
        #pragma unroll
        for (int j = 0; j < (BB * MM) / NTHREADS; ++j)
            out[j * NTHREADS + tid] = 0.0f;
    } else {
        // ---- softmax for sequence b
        const int b = blk - 9;
        const int wave = tid >> 6, lane = tid & 63;
        const int g0 = x[b * LL + tid];
        const int g1 = x[b * LL + tid + 256];
        const float v0 = mix_table[g0];
        const float v1 = mix_table[g1];
        float lmax = fmaxf(v0, v1);
        #pragma unroll
        for (int off = 32; off > 0; off >>= 1)
            lmax = fmaxf(lmax, __shfl_down(lmax, off));
        if (lane == 0) s_red[wave] = lmax;
        __syncthreads();
        const float bmax = fmaxf(fmaxf(s_red[0], s_red[1]), fmaxf(s_red[2], s_red[3]));
        const float e0 = __expf(v0 - bmax);
        const float e1 = __expf(v1 - bmax);
        float esum = e0 + e1;
        #pragma unroll
        for (int off = 32; off > 0; off >>= 1)
            esum += __shfl_down(esum, off);
        if (lane == 0) s_red[4 + wave] = esum;
        __syncthreads();
        const float inv = 1.0f / (s_red[4] + s_red[5] + s_red[6] + s_red[7]);
        ws_w[b * LL + tid]       = e0 * inv;
        ws_w[b * LL + tid + 256] = e1 * inv;
    }
}

// Main: 512 blocks = 64 b x 8 chunks of 64 tokens. One barrier total:
// [gather V (float2) + sincos + bf16 split -> LDS] -> barrier ->
// [split-bf16 MFMA (hh+hl+lh; ll dropped, ~2^-18 rel) + fused w-|A|^2 epilogue].
__global__ void __launch_bounds__(NTHREADS)
qdnn_main(const int*   __restrict__ x,
          const float* __restrict__ amp_table,
          const float* __restrict__ pha_table,
          const short* __restrict__ ws_frag,
          const float* __restrict__ ws_inorm,
          const float* __restrict__ ws_w,
          float* __restrict__ out)
{
    __shared__ short s_vhi[LT * KS];     // 17408 B  V = [vr|vi] bf16-hi
    __shared__ short s_vlo[LT * KS];     // 17408 B  bf16-lo residual
    __shared__ float s_w64[LT];          // total ~35 KB

    const int tid    = threadIdx.x;
    const int b      = blockIdx.x >> 3;
    const int lchunk = blockIdx.x & 7;
    const int wave   = tid >> 6;
    const int lane   = tid & 63;

    // ---- phase A: build V tile (4 threads per token, float2 pair lanes e=t4+4j)
    {
        const int tok = tid >> 2;
        const int t4  = tid & 3;
        const int gidx = x[b * LL + lchunk * LT + tok];   // 4 threads broadcast-load
        const float* arow = amp_table + (size_t)gidx * D; // row base byte = gidx*200, 8B-aligned
        const float* prow = pha_table + (size_t)gidx * D;
        unsigned* vhiU = (unsigned*)s_vhi;
        unsigned* vloU = (unsigned*)s_vlo;
        const int rb = tok * KSU;
        #pragma unroll
        for (int j = 0; j < 7; ++j) {
            const int e = t4 + 4 * j;                     // pair index, d = 2e
            if (e < 25) {
                const float2 a2 = *(const float2*)(arow + 2 * e);
                const float2 p2 = *(const float2*)(prow + 2 * e);
                float sn0, cs0, sn1, cs1;
                __sincosf(p2.x, &sn0, &cs0);
                __sincosf(p2.y, &sn1, &cs1);
                unsigned hu, lu;
                bsplit2(a2.x * cs0, a2.y * cs1, hu, lu);  // vr pair -> d, d+1
                vhiU[rb + e] = hu;  vloU[rb + e] = lu;
                bsplit2(a2.x * sn0, a2.y * sn1, hu, lu);  // vi pair -> D+d (50+2e, even)
                vhiU[rb + 25 + e] = hu;  vloU[rb + 25 + e] = lu;
            }
        }
        // zero K-pad uints [50,68) per row
        for (int j = tid; j < LT * (KSU - 50); j += NTHREADS) {
            const int r = j / (KSU - 50);
            const int c = j - r * (KSU - 50);
            vhiU[r * KSU + 50 + c] = 0;
            vloU[r * KSU + 50 + c] = 0;
        }
        if (tid < LT) s_w64[tid] = ws_w[b * LL + lchunk * LT + tid];
    }
    __syncthreads();

    // ---- phase B: MFMA GEMM + fused epilogue (barrier-free)
    const int l15 = lane & 15;           // A-row within 16-token tile; also output m-col
    const int g   = lane >> 4;
    #pragma unroll
    for (int miter = 0; miter < 2; ++miter) {
        const int ntile = miter * 4 + wave;      // waves cover m-tiles 0..7
        short8 fr_hi[4], fr_lo[4], fi_hi[4], fi_lo[4];
        #pragma unroll
        for (int ks = 0; ks < 4; ++ks) {
            const size_t fb = (size_t)((ntile * 4 + ks) * 4) * 64 * 8;
            fr_hi[ks] = *(const short8*)(ws_frag + fb + (size_t)(0 * 64 + lane) * 8);
            fr_lo[ks] = *(const short8*)(ws_frag + fb + (size_t)(1 * 64 + lane) * 8);
            fi_hi[ks] = *(const short8*)(ws_frag + fb + (size_t)(2 * 64 + lane) * 8);
            fi_lo[ks] = *(const short8*)(ws_frag + fb + (size_t)(3 * 64 + lane) * 8);
        }
        const float inrm = ws_inorm[ntile * 16 + l15];

        float pm = 0.0f;
        #pragma unroll
        for (int liter = 0; liter < 4; ++liter) {
            const int lb = liter * 16;
            float4v ar[4], ai[4];
            #pragma unroll
            for (int ks = 0; ks < 4; ++ks) {
                ar[ks] = (float4v)(0.0f);
                ai[ks] = (float4v)(0.0f);
            }
            #pragma unroll
            for (int ks = 0; ks < 4; ++ks) {     // 8 independent acc chains of 3
                const int aoff = (lb + l15) * KS + ks * 32 + g * 8;
                const short8 ah = *(const short8*)(s_vhi + aoff);
                const short8 al = *(const short8*)(s_vlo + aoff);
                ar[ks] = __builtin_amdgcn_mfma_f32_16x16x32_bf16(ah, fr_hi[ks], ar[ks], 0, 0, 0);
                ar[ks] = __builtin_amdgcn_mfma_f32_16x16x32_bf16(ah, fr_lo[ks], ar[ks], 0, 0, 0);
                ar[ks] = __builtin_amdgcn_mfma_f32_16x16x32_bf16(al, fr_hi[ks], ar[ks], 0, 0, 0);
                ai[ks] = __builtin_amdgcn_mfma_f32_16x16x32_bf16(ah, fi_hi[ks], ai[ks], 0, 0, 0);
                ai[ks] = __builtin_amdgcn_mfma_f32_16x16x32_bf16(ah, fi_lo[ks], ai[ks], 0, 0, 0);
                ai[ks] = __builtin_amdgcn_mfma_f32_16x16x32_bf16(al, fi_hi[ks], ai[ks], 0, 0, 0);
            }
            // C/D layout: col = lane&15 (m), row = g*4 + reg (token within tile)
            #pragma unroll
            for (int reg = 0; reg < 4; ++reg) {
                const float arr = ar[0][reg] + ar[1][reg] + ar[2][reg] + ar[3][reg];
                const float aii = ai[0][reg] + ai[1][reg] + ai[2][reg] + ai[3][reg];
                const float wl  = s_w64[lb + g * 4 + reg];
                pm = fmaf(wl, fmaf(arr, arr, aii * aii), pm);
            }
        }
        pm += __shfl_xor(pm, 16);
        pm += __shfl_xor(pm, 32);
        if (lane < 16)
            atomicAdd(&out[b * MM + ntile * 16 + l15], pm * inrm);
    }
}

extern "C" void kernel_launch(void* const* d_in, const int* in_sizes, int n_in,
                              void* d_out, int out_size, void* d_ws, size_t ws_size,
                              hipStream_t stream) {
    const int*   xx  = (const int*)d_in[0];
    const float* amp = (const float*)d_in[1];
    const float* pha = (const float*)d_in[2];
    const float* mix = (const float*)d_in[3];
    const float* kr  = (const float*)d_in[4];
    const float* ki  = (const float*)d_in[5];
    float* out = (float*)d_out;

    short* ws_frag  = (short*)d_ws;                        // 131072 B
    float* ws_inorm = (float*)((char*)d_ws + 131072);      //    512 B
    float* ws_w     = (float*)((char*)d_ws + 131584);      // 131072 B

    // prep: fragments (0..7) + out zero (8) + per-b softmax (9..72)
    hipLaunchKernelGGL(qdnn_prep, dim3(9 + BB), dim3(NTHREADS), 0, stream,
                       xx, mix, kr, ki, out, ws_frag, ws_inorm, ws_w);
    // main: 512 blocks = 64 b x 8 token-chunks
    hipLaunchKernelGGL(qdnn_main, dim3(BB * NCH), dim3(NTHREADS), 0, stream,
                       xx, amp, pha, ws_frag, ws_inorm, ws_w, out);
}